// Round 1
// baseline (570.436 us; speedup 1.0000x reference)
//
#include <hip/hip_runtime.h>
#include <stdint.h>

typedef unsigned short u16;
typedef short bf16x8 __attribute__((ext_vector_type(8)));
typedef float f32x4 __attribute__((ext_vector_type(4)));
typedef u16 u16x4 __attribute__((ext_vector_type(4)));
typedef u16 u16x8 __attribute__((ext_vector_type(8)));

#define B_SZ   1024
#define D_IN   400
#define L_OUT  392
#define OC     32
#define KW     9
#define K_FC   12544   /* OC*L_OUT */
#define N_ENT  50000
#define NPAD_ENT 50048 /* 391*128 */
#define KPAD_H 448     /* 400 -> 7*64 */
#define NPAD_FC 512    /* 400 -> 4*128 */

__device__ __forceinline__ u16 f2bf(float f) {
  uint32_t u = __builtin_bit_cast(uint32_t, f);
  u += 0x7FFFu + ((u >> 16) & 1u);
  return (u16)(u >> 16);
}
__device__ __forceinline__ float bf2f(u16 v) {
  uint32_t u = ((uint32_t)v) << 16;
  return __builtin_bit_cast(float, u);
}

__device__ __forceinline__ void gload_lds16(const u16* g, u16* l) {
  __builtin_amdgcn_global_load_lds(
      (const __attribute__((address_space(1))) unsigned int*)g,
      (__attribute__((address_space(3))) unsigned int*)l, 16, 0, 0);
}

// reduce (s1,s2) across a 256-thread block; result valid in thread 0 only
__device__ __forceinline__ void block_reduce2(float& s1, float& s2, float* sm) {
  for (int d = 32; d; d >>= 1) { s1 += __shfl_down(s1, d); s2 += __shfl_down(s2, d); }
  int wave = threadIdx.x >> 6, lane = threadIdx.x & 63;
  if (lane == 0) { sm[wave * 2] = s1; sm[wave * 2 + 1] = s2; }
  __syncthreads();
  if (threadIdx.x == 0) {
    s1 = sm[0] + sm[2] + sm[4] + sm[6];
    s2 = sm[1] + sm[3] + sm[5] + sm[7];
  }
}

// ---------- bn0 stage ----------
__global__ __launch_bounds__(256) void red0(const float* __restrict__ e1, float* __restrict__ part0) {
  int t = threadIdx.x;
  int idx = blockIdx.x * 256 + t;
  float s1 = 0.f, s2 = 0.f;
  for (int i = idx; i < B_SZ * D_IN; i += 256 * 256) { float v = e1[i]; s1 += v; s2 += v * v; }
  __shared__ float sm[8];
  block_reduce2(s1, s2, sm);
  if (t == 0) { part0[blockIdx.x * 2] = s1; part0[blockIdx.x * 2 + 1] = s2; }
}

__global__ __launch_bounds__(256) void comb0(const float* __restrict__ part0,
                                             const float* __restrict__ g0,
                                             const float* __restrict__ b0,
                                             float* __restrict__ stats) {
  int t = threadIdx.x;
  float s1 = part0[t * 2], s2 = part0[t * 2 + 1];
  __shared__ float sm[8];
  block_reduce2(s1, s2, sm);
  if (t == 0) {
    const float N = (float)(B_SZ * D_IN);
    float mu = s1 / N, var = s2 / N - mu * mu;
    float a = g0[0] * rsqrtf(var + 1e-5f);
    stats[0] = a;
    stats[1] = b0[0] - mu * a;
  }
}

// ---------- fc1: k = rel @ fc1_w^T + fc1_b  (fp32, tiny) ----------
__global__ __launch_bounds__(256) void fc1_gemm(const float* __restrict__ rel,
                                                const float* __restrict__ W,
                                                const float* __restrict__ bias,
                                                float* __restrict__ outk) {
  __shared__ __align__(16) float As[16 * 68];
  __shared__ __align__(16) float Bs[16 * 68];
  int mt = blockIdx.x, nt = blockIdx.y;
  int t = threadIdx.x;
  int tx = t & 15, ty = t >> 4;
  int lr = t >> 2, lk = (t & 3) * 4;
  float acc[4][4] = {};
  for (int k0 = 0; k0 < 400; k0 += 16) {
    __syncthreads();
    float4 av = *(const float4*)(rel + (size_t)(mt * 64 + lr) * 400 + k0 + lk);
    int brow = nt * 64 + lr;
    float4 bv = {0.f, 0.f, 0.f, 0.f};
    if (brow < 288) bv = *(const float4*)(W + (size_t)brow * 400 + k0 + lk);
    As[(lk + 0) * 68 + lr] = av.x; As[(lk + 1) * 68 + lr] = av.y;
    As[(lk + 2) * 68 + lr] = av.z; As[(lk + 3) * 68 + lr] = av.w;
    Bs[(lk + 0) * 68 + lr] = bv.x; Bs[(lk + 1) * 68 + lr] = bv.y;
    Bs[(lk + 2) * 68 + lr] = bv.z; Bs[(lk + 3) * 68 + lr] = bv.w;
    __syncthreads();
#pragma unroll
    for (int k = 0; k < 16; ++k) {
      float4 a = *(const float4*)(As + k * 68 + ty * 4);
      float4 b = *(const float4*)(Bs + k * 68 + tx * 4);
      float aa[4] = {a.x, a.y, a.z, a.w}, bb[4] = {b.x, b.y, b.z, b.w};
#pragma unroll
      for (int i = 0; i < 4; ++i)
#pragma unroll
        for (int j = 0; j < 4; ++j) acc[i][j] += aa[i] * bb[j];
    }
  }
#pragma unroll
  for (int i = 0; i < 4; ++i) {
    int row = mt * 64 + ty * 4 + i;
#pragma unroll
    for (int j = 0; j < 4; ++j) {
      int col = nt * 64 + tx * 4 + j;
      if (col < 288) outk[(size_t)row * 288 + col] = acc[i][j] + bias[col];
    }
  }
}

// ---------- conv + bn1 partial stats; conv stored as bf16 ----------
__global__ __launch_bounds__(256) void conv_kernel(const float* __restrict__ e1,
                                                   const float* __restrict__ stats,
                                                   const float* __restrict__ kbuf,
                                                   u16* __restrict__ convA,
                                                   float* __restrict__ partial1) {
  int b = blockIdx.x, t = threadIdx.x;
  __shared__ __align__(16) float xs[D_IN];
  __shared__ float ks[OC * KW];
  float a0 = stats[0], b0c = stats[1];
  for (int i = t; i < D_IN; i += 256) xs[i] = e1[(size_t)b * D_IN + i] * a0 + b0c;
  for (int i = t; i < OC * KW; i += 256) ks[i] = kbuf[(size_t)b * (OC * KW) + i];
  __syncthreads();
  int o = t >> 3, sub = t & 7;
  float kw[KW];
#pragma unroll
  for (int w = 0; w < KW; ++w) kw[w] = ks[o * KW + w];
  float s1 = 0.f, s2 = 0.f;
  u16* orow = convA + (size_t)b * K_FC + o * L_OUT;
#pragma unroll
  for (int it = 0; it < 13; ++it) {
    int l = sub * 4 + it * 32;
    if (l < L_OUT) {
      float4 x0 = *(const float4*)(xs + l);
      float4 x1 = *(const float4*)(xs + l + 4);
      float4 x2 = *(const float4*)(xs + l + 8);
      float xv[12] = {x0.x, x0.y, x0.z, x0.w, x1.x, x1.y, x1.z, x1.w, x2.x, x2.y, x2.z, x2.w};
      u16x4 st;
#pragma unroll
      for (int j = 0; j < 4; ++j) {
        float c = 0.f;
#pragma unroll
        for (int w = 0; w < KW; ++w) c += xv[j + w] * kw[w];
        s1 += c; s2 += c * c;
        st[j] = f2bf(c);
      }
      *(u16x4*)(orow + l) = st;
    }
  }
  s1 += __shfl_down(s1, 4); s2 += __shfl_down(s2, 4);
  s1 += __shfl_down(s1, 2); s2 += __shfl_down(s2, 2);
  s1 += __shfl_down(s1, 1); s2 += __shfl_down(s2, 1);
  if (sub == 0) {
    partial1[b * 64 + o] = s1;
    partial1[b * 64 + 32 + o] = s2;
  }
}

// ---------- bn1 combine + expand alpha/beta over k ----------
__global__ __launch_bounds__(256) void comb1(const float* __restrict__ partial1,
                                             const float* __restrict__ g1,
                                             const float* __restrict__ b1,
                                             float* __restrict__ alphaK,
                                             float* __restrict__ betaK) {
  __shared__ float red[256];
  __shared__ float ab[64];
  int t = threadIdx.x;
  int s = t & 63, q = t >> 6;
  float acc = 0.f;
  for (int b = q * 256; b < q * 256 + 256; ++b) acc += partial1[b * 64 + s];
  red[t] = acc;
  __syncthreads();
  if (t < 64) red[t] = red[t] + red[t + 64] + red[t + 128] + red[t + 192];
  __syncthreads();
  if (t < 32) {
    const float N = (float)(B_SZ * L_OUT);
    float S1 = red[t], S2 = red[t + 32];
    float mu = S1 / N, var = S2 / N - mu * mu;
    float al = g1[t] * rsqrtf(var + 1e-5f);
    ab[t] = al;
    ab[32 + t] = b1[t] - mu * al;
  }
  __syncthreads();
  for (int i = t; i < K_FC; i += 256) {
    int o = i / L_OUT;
    alphaK[i] = ab[o];
    betaK[i] = ab[32 + o];
  }
}

// ---------- apply bn1 affine to convA in place (bf16) ----------
__global__ __launch_bounds__(256) void bn1_apply(u16* __restrict__ convA,
                                                 const float* __restrict__ alphaK,
                                                 const float* __restrict__ betaK) {
  int gid = blockIdx.x * 256 + threadIdx.x;       // 1024*1568 threads
  int row = gid / 1568, c = gid - row * 1568;
  int k = c * 8;
  u16* p = convA + (size_t)row * K_FC + k;
  u16x8 v = *(u16x8*)p;
  float4 a0 = *(const float4*)(alphaK + k);
  float4 a1 = *(const float4*)(alphaK + k + 4);
  float4 b0 = *(const float4*)(betaK + k);
  float4 b1 = *(const float4*)(betaK + k + 4);
  u16x8 o;
  o[0] = f2bf(bf2f(v[0]) * a0.x + b0.x);
  o[1] = f2bf(bf2f(v[1]) * a0.y + b0.y);
  o[2] = f2bf(bf2f(v[2]) * a0.z + b0.z);
  o[3] = f2bf(bf2f(v[3]) * a0.w + b0.w);
  o[4] = f2bf(bf2f(v[4]) * a1.x + b1.x);
  o[5] = f2bf(bf2f(v[5]) * a1.y + b1.y);
  o[6] = f2bf(bf2f(v[6]) * a1.z + b1.z);
  o[7] = f2bf(bf2f(v[7]) * a1.w + b1.w);
  *(u16x8*)p = o;
}

// ---------- converters ----------
__global__ __launch_bounds__(256) void cvt_fcw(const float* __restrict__ src, u16* __restrict__ dst) {
  int gid = blockIdx.x * 256 + threadIdx.x;       // 512*1568 threads
  int row = gid / 1568, c = gid - row * 1568;
  int k = c * 8;
  u16x8 o = {};
  if (row < 400) {
    float4 f0 = *(const float4*)(src + (size_t)row * K_FC + k);
    float4 f1 = *(const float4*)(src + (size_t)row * K_FC + k + 4);
    o[0] = f2bf(f0.x); o[1] = f2bf(f0.y); o[2] = f2bf(f0.z); o[3] = f2bf(f0.w);
    o[4] = f2bf(f1.x); o[5] = f2bf(f1.y); o[6] = f2bf(f1.z); o[7] = f2bf(f1.w);
  }
  *(u16x8*)(dst + (size_t)row * K_FC + k) = o;
}

__global__ __launch_bounds__(256) void cvt_ent(const float* __restrict__ src, u16* __restrict__ dst) {
  int gid = blockIdx.x * 256 + threadIdx.x;       // 50048*56 threads
  int row = gid / 56, c = gid - row * 56;
  int k = c * 8;
  u16x8 o = {};
  if (row < N_ENT && k < D_IN) {
    float4 f0 = *(const float4*)(src + (size_t)row * D_IN + k);
    float4 f1 = *(const float4*)(src + (size_t)row * D_IN + k + 4);
    o[0] = f2bf(f0.x); o[1] = f2bf(f0.y); o[2] = f2bf(f0.z); o[3] = f2bf(f0.w);
    o[4] = f2bf(f1.x); o[5] = f2bf(f1.y); o[6] = f2bf(f1.z); o[7] = f2bf(f1.w);
  }
  *(u16x8*)(dst + (size_t)row * KPAD_H + k) = o;
}

// ---------- bn2 + relu -> hfin (bf16, padded to 448) ----------
__global__ __launch_bounds__(256) void bn2_kernel(const float* __restrict__ part2,
                                                  const float* __restrict__ g2,
                                                  const float* __restrict__ b2,
                                                  u16* __restrict__ hfin) {
  int j = blockIdx.x, t = threadIdx.x;
  if (j >= D_IN) {  // zero the K padding columns
    for (int b = t; b < B_SZ; b += 256) hfin[(size_t)b * KPAD_H + j] = 0;
    return;
  }
  float v[4], s1 = 0.f, s2 = 0.f;
#pragma unroll
  for (int i = 0; i < 4; ++i) {
    int b = t + i * 256;
    float acc = 0.f;
#pragma unroll
    for (int s = 0; s < 8; ++s) acc += part2[((size_t)s * B_SZ + b) * NPAD_FC + j];
    v[i] = acc; s1 += acc; s2 += acc * acc;
  }
  __shared__ float sm[8];
  block_reduce2(s1, s2, sm);
  __shared__ float albe[2];
  if (t == 0) {
    float mu = s1 / 1024.f, var = s2 / 1024.f - mu * mu;
    float al = g2[j] * rsqrtf(var + 1e-5f);
    albe[0] = al; albe[1] = b2[j] - mu * al;
  }
  __syncthreads();
  float al = albe[0], be = albe[1];
#pragma unroll
  for (int i = 0; i < 4; ++i) {
    float h = fmaxf(v[i] * al + be, 0.f);
    hfin[(size_t)(t + i * 256) * KPAD_H + j] = f2bf(h);
  }
}

// ---------- bf16 MFMA GEMM: C = A[M,Kpad] @ B[N,Kpad]^T  (m97-style) ----------
__global__ __launch_bounds__(256) void gemm_bt(const u16* __restrict__ A,
                                               const u16* __restrict__ Bm,
                                               float* __restrict__ C,
                                               int Kpad, int mtiles, int ntiles,
                                               int ksteps_total, int ksteps_chunk,
                                               long ldc, int ncols_valid, long csplit_stride) {
  __shared__ __align__(16) u16 As[128 * 64];
  __shared__ __align__(16) u16 Bs[128 * 64];
  int bid = blockIdx.x;
  int mt = bid % mtiles;
  int nt = (bid / mtiles) % ntiles;
  int sp = bid / (mtiles * ntiles);
  int kbeg = sp * ksteps_chunk;
  int kend = kbeg + ksteps_chunk;
  if (kend > ksteps_total) kend = ksteps_total;

  int tid = threadIdx.x;
  int wave = tid >> 6, lane = tid & 63;
  int quad = lane >> 4, m16 = lane & 15;
  int rbase = (wave >> 1) * 64, cbase = (wave & 1) * 64;

  const u16* Arow0 = A + (size_t)mt * 128 * Kpad;
  const u16* Brow0 = Bm + (size_t)nt * 128 * Kpad;

  f32x4 acc[4][4] = {};

  for (int kt = kbeg; kt < kend; ++kt) {
    int k0 = kt * 64;
    __syncthreads();
#pragma unroll
    for (int p = 0; p < 4; ++p) {
      int slin = p * 256 + tid;
      int row = slin >> 3;
      int gch = (slin & 7) ^ (row & 7);            // XOR-8 swizzle, conflict-free reads
      u16* la = As + ((p * 256 + (wave << 6)) << 3);
      u16* lb = Bs + ((p * 256 + (wave << 6)) << 3);
      gload_lds16(Arow0 + (size_t)row * Kpad + k0 + gch * 8, la);
      gload_lds16(Brow0 + (size_t)row * Kpad + k0 + gch * 8, lb);
    }
    __syncthreads();
#pragma unroll
    for (int s = 0; s < 2; ++s) {
      bf16x8 af[4], bfr[4];
#pragma unroll
      for (int i = 0; i < 4; ++i) {
        int ar = rbase + i * 16 + m16;
        af[i] = *(const bf16x8*)(As + ar * 64 + (((s * 4 + quad) ^ (ar & 7)) << 3));
        int bc = cbase + i * 16 + m16;
        bfr[i] = *(const bf16x8*)(Bs + bc * 64 + (((s * 4 + quad) ^ (bc & 7)) << 3));
      }
#pragma unroll
      for (int i = 0; i < 4; ++i)
#pragma unroll
        for (int j = 0; j < 4; ++j)
          acc[i][j] = __builtin_amdgcn_mfma_f32_16x16x32_bf16(af[i], bfr[j], acc[i][j], 0, 0, 0);
    }
  }

  float* Cb = C + (size_t)sp * csplit_stride;
#pragma unroll
  for (int i = 0; i < 4; ++i) {
#pragma unroll
    for (int j = 0; j < 4; ++j) {
      int col = nt * 128 + cbase + j * 16 + m16;
      if (col < ncols_valid) {
        int row0 = mt * 128 + rbase + i * 16 + quad * 4;
#pragma unroll
        for (int r = 0; r < 4; ++r)
          Cb[(size_t)(row0 + r) * ldc + col] = acc[i][j][r];
      }
    }
  }
}

extern "C" void kernel_launch(void* const* d_in, const int* in_sizes, int n_in,
                              void* d_out, int out_size, void* d_ws, size_t ws_size,
                              hipStream_t stream) {
  const float* e1   = (const float*)d_in[0];
  const float* rel  = (const float*)d_in[1];
  const float* entw = (const float*)d_in[2];
  const float* fc1w = (const float*)d_in[3];
  const float* fc1b = (const float*)d_in[4];
  const float* fcw  = (const float*)d_in[5];
  // d_in[6] = fc_b: cancels exactly under bn2 mean subtraction (and is zero)
  const float* bn0g = (const float*)d_in[7];
  const float* bn0b = (const float*)d_in[8];
  const float* bn1g = (const float*)d_in[9];
  const float* bn1b = (const float*)d_in[10];
  const float* bn2g = (const float*)d_in[11];
  const float* bn2b = (const float*)d_in[12];
  float* out = (float*)d_out;

  char* ws = (char*)d_ws;
  size_t off = 0;
  auto alloc = [&](size_t bytes) -> void* {
    off = (off + 255) & ~(size_t)255;
    void* p = ws + off;
    off += bytes;
    return p;
  };
  float* stats    = (float*)alloc(16 * 4);
  float* part0    = (float*)alloc(512 * 4);
  float* kbuf     = (float*)alloc((size_t)B_SZ * 288 * 4);
  float* partial1 = (float*)alloc((size_t)B_SZ * 64 * 4);
  float* alphaK   = (float*)alloc((size_t)K_FC * 4);
  float* betaK    = (float*)alloc((size_t)K_FC * 4);
  u16*   convA    = (u16*)alloc((size_t)B_SZ * K_FC * 2);
  u16*   fcwb     = (u16*)alloc((size_t)NPAD_FC * K_FC * 2);
  float* part2    = (float*)alloc((size_t)8 * B_SZ * NPAD_FC * 4);
  u16*   hfin     = (u16*)alloc((size_t)B_SZ * KPAD_H * 2);
  u16*   entb     = (u16*)alloc((size_t)NPAD_ENT * KPAD_H * 2);

  red0<<<256, 256, 0, stream>>>(e1, part0);
  comb0<<<1, 256, 0, stream>>>(part0, bn0g, bn0b, stats);
  fc1_gemm<<<dim3(16, 5), 256, 0, stream>>>(rel, fc1w, fc1b, kbuf);
  conv_kernel<<<B_SZ, 256, 0, stream>>>(e1, stats, kbuf, convA, partial1);
  comb1<<<1, 256, 0, stream>>>(partial1, bn1g, bn1b, alphaK, betaK);
  bn1_apply<<<6272, 256, 0, stream>>>(convA, alphaK, betaK);
  cvt_fcw<<<3136, 256, 0, stream>>>(fcw, fcwb);
  // fc GEMM: M=1024, N=512(pad of 400), K=12544 -> split-K=8 deterministic partials
  gemm_bt<<<8 * 4 * 8, 256, 0, stream>>>(convA, fcwb, part2, K_FC, 8, 4, 196, 25,
                                         (long)NPAD_FC, NPAD_FC, (long)B_SZ * NPAD_FC);
  bn2_kernel<<<KPAD_H, 256, 0, stream>>>(part2, bn2g, bn2b, hfin);
  cvt_ent<<<10948, 256, 0, stream>>>(entw, entb);
  // final GEMM: M=1024, N=50048(pad of 50000), K=448(pad of 400), m-fastest for B-tile L2 reuse
  gemm_bt<<<8 * 391, 256, 0, stream>>>(hfin, entb, out, KPAD_H, 8, 391, 7, 7,
                                       (long)N_ENT, N_ENT, 0);
}

// Round 2
// 555.387 us; speedup vs baseline: 1.0271x; 1.0271x over previous
//
#include <hip/hip_runtime.h>
#include <stdint.h>

typedef unsigned short u16;
typedef short bf16x8 __attribute__((ext_vector_type(8)));
typedef float f32x4 __attribute__((ext_vector_type(4)));
typedef u16 u16x4 __attribute__((ext_vector_type(4)));
typedef u16 u16x8 __attribute__((ext_vector_type(8)));

#define B_SZ   1024
#define D_IN   400
#define L_OUT  392
#define OC     32
#define KW     9
#define K_FC   12544   /* OC*L_OUT */
#define N_ENT  50000
#define NPAD_ENT 50048 /* 391*128 */
#define KPAD_H 448     /* 400 -> 7*64 */
#define NPAD_FC 512    /* 400 -> 4*128 */
#define SPLIT_FC 14    /* 196 ksteps = 14*14, perfectly balanced */

__device__ __forceinline__ u16 f2bf(float f) {
  uint32_t u = __builtin_bit_cast(uint32_t, f);
  u += 0x7FFFu + ((u >> 16) & 1u);
  return (u16)(u >> 16);
}
__device__ __forceinline__ float bf2f(u16 v) {
  uint32_t u = ((uint32_t)v) << 16;
  return __builtin_bit_cast(float, u);
}

__device__ __forceinline__ void gload_lds16(const u16* g, u16* l) {
  __builtin_amdgcn_global_load_lds(
      (const __attribute__((address_space(1))) unsigned int*)g,
      (__attribute__((address_space(3))) unsigned int*)l, 16, 0, 0);
}

// reduce (s1,s2) across a 256-thread block; result valid in thread 0 only
__device__ __forceinline__ void block_reduce2(float& s1, float& s2, float* sm) {
  for (int d = 32; d; d >>= 1) { s1 += __shfl_down(s1, d); s2 += __shfl_down(s2, d); }
  int wave = threadIdx.x >> 6, lane = threadIdx.x & 63;
  if (lane == 0) { sm[wave * 2] = s1; sm[wave * 2 + 1] = s2; }
  __syncthreads();
  if (threadIdx.x == 0) {
    s1 = sm[0] + sm[2] + sm[4] + sm[6];
    s2 = sm[1] + sm[3] + sm[5] + sm[7];
  }
}

// ---------- bn0 stage ----------
__global__ __launch_bounds__(256) void red0(const float* __restrict__ e1, float* __restrict__ part0) {
  int t = threadIdx.x;
  int idx = blockIdx.x * 256 + t;
  float s1 = 0.f, s2 = 0.f;
  for (int i = idx; i < B_SZ * D_IN; i += 256 * 256) { float v = e1[i]; s1 += v; s2 += v * v; }
  __shared__ float sm[8];
  block_reduce2(s1, s2, sm);
  if (t == 0) { part0[blockIdx.x * 2] = s1; part0[blockIdx.x * 2 + 1] = s2; }
}

__global__ __launch_bounds__(256) void comb0(const float* __restrict__ part0,
                                             const float* __restrict__ g0,
                                             const float* __restrict__ b0,
                                             float* __restrict__ stats) {
  int t = threadIdx.x;
  float s1 = part0[t * 2], s2 = part0[t * 2 + 1];
  __shared__ float sm[8];
  block_reduce2(s1, s2, sm);
  if (t == 0) {
    const float N = (float)(B_SZ * D_IN);
    float mu = s1 / N, var = s2 / N - mu * mu;
    float a = g0[0] * rsqrtf(var + 1e-5f);
    stats[0] = a;
    stats[1] = b0[0] - mu * a;
  }
}

// ---------- fc1: k = rel @ fc1_w^T + fc1_b  (fp32, tiny) ----------
__global__ __launch_bounds__(256) void fc1_gemm(const float* __restrict__ rel,
                                                const float* __restrict__ W,
                                                const float* __restrict__ bias,
                                                float* __restrict__ outk) {
  __shared__ __align__(16) float As[16 * 68];
  __shared__ __align__(16) float Bs[16 * 68];
  int mt = blockIdx.x, nt = blockIdx.y;
  int t = threadIdx.x;
  int tx = t & 15, ty = t >> 4;
  int lr = t >> 2, lk = (t & 3) * 4;
  float acc[4][4] = {};
  for (int k0 = 0; k0 < 400; k0 += 16) {
    __syncthreads();
    float4 av = *(const float4*)(rel + (size_t)(mt * 64 + lr) * 400 + k0 + lk);
    int brow = nt * 64 + lr;
    float4 bv = {0.f, 0.f, 0.f, 0.f};
    if (brow < 288) bv = *(const float4*)(W + (size_t)brow * 400 + k0 + lk);
    As[(lk + 0) * 68 + lr] = av.x; As[(lk + 1) * 68 + lr] = av.y;
    As[(lk + 2) * 68 + lr] = av.z; As[(lk + 3) * 68 + lr] = av.w;
    Bs[(lk + 0) * 68 + lr] = bv.x; Bs[(lk + 1) * 68 + lr] = bv.y;
    Bs[(lk + 2) * 68 + lr] = bv.z; Bs[(lk + 3) * 68 + lr] = bv.w;
    __syncthreads();
#pragma unroll
    for (int k = 0; k < 16; ++k) {
      float4 a = *(const float4*)(As + k * 68 + ty * 4);
      float4 b = *(const float4*)(Bs + k * 68 + tx * 4);
      float aa[4] = {a.x, a.y, a.z, a.w}, bb[4] = {b.x, b.y, b.z, b.w};
#pragma unroll
      for (int i = 0; i < 4; ++i)
#pragma unroll
        for (int j = 0; j < 4; ++j) acc[i][j] += aa[i] * bb[j];
    }
  }
#pragma unroll
  for (int i = 0; i < 4; ++i) {
    int row = mt * 64 + ty * 4 + i;
#pragma unroll
    for (int j = 0; j < 4; ++j) {
      int col = nt * 64 + tx * 4 + j;
      if (col < 288) outk[(size_t)row * 288 + col] = acc[i][j] + bias[col];
    }
  }
}

// ---------- conv + bn1 partial stats; raw conv stored as bf16 ----------
__global__ __launch_bounds__(256) void conv_kernel(const float* __restrict__ e1,
                                                   const float* __restrict__ stats,
                                                   const float* __restrict__ kbuf,
                                                   u16* __restrict__ convA,
                                                   float* __restrict__ partial1) {
  int b = blockIdx.x, t = threadIdx.x;
  __shared__ __align__(16) float xs[D_IN];
  __shared__ float ks[OC * KW];
  float a0 = stats[0], b0c = stats[1];
  for (int i = t; i < D_IN; i += 256) xs[i] = e1[(size_t)b * D_IN + i] * a0 + b0c;
  for (int i = t; i < OC * KW; i += 256) ks[i] = kbuf[(size_t)b * (OC * KW) + i];
  __syncthreads();
  int o = t >> 3, sub = t & 7;
  float kw[KW];
#pragma unroll
  for (int w = 0; w < KW; ++w) kw[w] = ks[o * KW + w];
  float s1 = 0.f, s2 = 0.f;
  u16* orow = convA + (size_t)b * K_FC + o * L_OUT;
#pragma unroll
  for (int it = 0; it < 13; ++it) {
    int l = sub * 4 + it * 32;
    if (l < L_OUT) {
      float4 x0 = *(const float4*)(xs + l);
      float4 x1 = *(const float4*)(xs + l + 4);
      float4 x2 = *(const float4*)(xs + l + 8);
      float xv[12] = {x0.x, x0.y, x0.z, x0.w, x1.x, x1.y, x1.z, x1.w, x2.x, x2.y, x2.z, x2.w};
      u16x4 st;
#pragma unroll
      for (int j = 0; j < 4; ++j) {
        float c = 0.f;
#pragma unroll
        for (int w = 0; w < KW; ++w) c += xv[j + w] * kw[w];
        s1 += c; s2 += c * c;
        st[j] = f2bf(c);
      }
      *(u16x4*)(orow + l) = st;
    }
  }
  s1 += __shfl_down(s1, 4); s2 += __shfl_down(s2, 4);
  s1 += __shfl_down(s1, 2); s2 += __shfl_down(s2, 2);
  s1 += __shfl_down(s1, 1); s2 += __shfl_down(s2, 1);
  if (sub == 0) {
    partial1[b * 64 + o] = s1;
    partial1[b * 64 + 32 + o] = s2;
  }
}

// ---------- bn1 combine -> expanded alpha over k (beta cancels under bn2) ----------
__global__ __launch_bounds__(256) void comb1(const float* __restrict__ partial1,
                                             const float* __restrict__ g1,
                                             float* __restrict__ alphaK) {
  __shared__ float red[256];
  __shared__ float ab[32];
  int t = threadIdx.x;
  int s = t & 63, q = t >> 6;
  float acc = 0.f;
  for (int b = q * 256; b < q * 256 + 256; ++b) acc += partial1[b * 64 + s];
  red[t] = acc;
  __syncthreads();
  if (t < 64) red[t] = red[t] + red[t + 64] + red[t + 128] + red[t + 192];
  __syncthreads();
  if (t < 32) {
    const float N = (float)(B_SZ * L_OUT);
    float S1 = red[t], S2 = red[t + 32];
    float mu = S1 / N, var = S2 / N - mu * mu;
    ab[t] = g1[t] * rsqrtf(var + 1e-5f);
  }
  __syncthreads();
  for (int i = t; i < K_FC; i += 256) {
    int o = i / L_OUT;
    alphaK[i] = ab[o];
  }
}

// ---------- converters ----------
// fc weights * alphaK -> bf16 (bn1 alpha folded into the weights)
__global__ __launch_bounds__(256) void cvt_fcw(const float* __restrict__ src,
                                               const float* __restrict__ alphaK,
                                               u16* __restrict__ dst) {
  int gid = blockIdx.x * 256 + threadIdx.x;       // 512*1568 threads
  int row = gid / 1568, c = gid - row * 1568;
  int k = c * 8;
  u16x8 o = {};
  if (row < 400) {
    float4 f0 = *(const float4*)(src + (size_t)row * K_FC + k);
    float4 f1 = *(const float4*)(src + (size_t)row * K_FC + k + 4);
    float4 a0 = *(const float4*)(alphaK + k);
    float4 a1 = *(const float4*)(alphaK + k + 4);
    o[0] = f2bf(f0.x * a0.x); o[1] = f2bf(f0.y * a0.y);
    o[2] = f2bf(f0.z * a0.z); o[3] = f2bf(f0.w * a0.w);
    o[4] = f2bf(f1.x * a1.x); o[5] = f2bf(f1.y * a1.y);
    o[6] = f2bf(f1.z * a1.z); o[7] = f2bf(f1.w * a1.w);
  }
  *(u16x8*)(dst + (size_t)row * K_FC + k) = o;
}

__global__ __launch_bounds__(256) void cvt_ent(const float* __restrict__ src, u16* __restrict__ dst) {
  int gid = blockIdx.x * 256 + threadIdx.x;       // 50048*56 threads
  int row = gid / 56, c = gid - row * 56;
  int k = c * 8;
  u16x8 o = {};
  if (row < N_ENT && k < D_IN) {
    float4 f0 = *(const float4*)(src + (size_t)row * D_IN + k);
    float4 f1 = *(const float4*)(src + (size_t)row * D_IN + k + 4);
    o[0] = f2bf(f0.x); o[1] = f2bf(f0.y); o[2] = f2bf(f0.z); o[3] = f2bf(f0.w);
    o[4] = f2bf(f1.x); o[5] = f2bf(f1.y); o[6] = f2bf(f1.z); o[7] = f2bf(f1.w);
  }
  *(u16x8*)(dst + (size_t)row * KPAD_H + k) = o;
}

// ---------- bn2 + relu -> hfin (bf16, padded to 448); coalesced ----------
// 28 blocks x 16 features; values cached in registers across both passes.
__global__ __launch_bounds__(256) void bn2_kernel(const float* __restrict__ part2,
                                                  const float* __restrict__ g2,
                                                  const float* __restrict__ b2,
                                                  u16* __restrict__ hfin) {
  int j0 = blockIdx.x * 16;
  int t = threadIdx.x;
  int tj = t & 15, tb = t >> 4;
  int j = j0 + tj;
  float v[64];
  float s1 = 0.f, s2 = 0.f;
#pragma unroll 2
  for (int i = 0; i < 64; ++i) {
    int b = tb + i * 16;
    float acc = 0.f;
#pragma unroll
    for (int s = 0; s < SPLIT_FC; ++s)
      acc += part2[((size_t)s * B_SZ + b) * NPAD_FC + j];
    v[i] = acc; s1 += acc; s2 += acc * acc;
  }
  __shared__ float sm1[16][17], sm2[16][17];
  sm1[tb][tj] = s1; sm2[tb][tj] = s2;
  __syncthreads();
  __shared__ float albe[2][16];
  if (t < 16) {
    float S1 = 0.f, S2 = 0.f;
#pragma unroll
    for (int r = 0; r < 16; ++r) { S1 += sm1[r][t]; S2 += sm2[r][t]; }
    int jf = j0 + t;
    float al = 0.f, be = 0.f;
    if (jf < D_IN) {
      float mu = S1 / 1024.f, var = S2 / 1024.f - mu * mu;
      al = g2[jf] * rsqrtf(var + 1e-5f);
      be = b2[jf] - mu * al;
    }
    albe[0][t] = al; albe[1][t] = be;
  }
  __syncthreads();
  float al = albe[0][tj], be = albe[1][tj];
#pragma unroll 2
  for (int i = 0; i < 64; ++i) {
    int b = tb + i * 16;
    hfin[(size_t)b * KPAD_H + j] = f2bf(fmaxf(v[i] * al + be, 0.f));
  }
}

// ---------- bf16 MFMA GEMM: C = A[M,Kpad] @ B[N,Kpad]^T  (m97-style) ----------
// xcd_swz=1: blocks sharing an n-tile get the same bid%8 residue (same XCD)
// so each B tile is fetched into exactly one XCD's L2.
__global__ __launch_bounds__(256) void gemm_bt(const u16* __restrict__ A,
                                               const u16* __restrict__ Bm,
                                               float* __restrict__ C,
                                               int Kpad, int mtiles, int ntiles,
                                               int ksteps_total, int ksteps_chunk,
                                               long ldc, int ncols_valid, long csplit_stride,
                                               int xcd_swz) {
  __shared__ __align__(16) u16 As[128 * 64];
  __shared__ __align__(16) u16 Bs[128 * 64];
  int bid = blockIdx.x;
  int mt, nt, sp;
  if (xcd_swz) {
    int r = bid & 7, g = bid >> 3;
    mt = g & 7;
    nt = (g >> 3) * 8 + r;
    sp = 0;
    if (nt >= ntiles) return;
  } else {
    mt = bid % mtiles;
    nt = (bid / mtiles) % ntiles;
    sp = bid / (mtiles * ntiles);
  }
  int kbeg = sp * ksteps_chunk;
  int kend = kbeg + ksteps_chunk;
  if (kend > ksteps_total) kend = ksteps_total;

  int tid = threadIdx.x;
  int wave = tid >> 6, lane = tid & 63;
  int quad = lane >> 4, m16 = lane & 15;
  int rbase = (wave >> 1) * 64, cbase = (wave & 1) * 64;

  const u16* Arow0 = A + (size_t)mt * 128 * Kpad;
  const u16* Brow0 = Bm + (size_t)nt * 128 * Kpad;

  f32x4 acc[4][4] = {};

  for (int kt = kbeg; kt < kend; ++kt) {
    int k0 = kt * 64;
    __syncthreads();
#pragma unroll
    for (int p = 0; p < 4; ++p) {
      int slin = p * 256 + tid;
      int row = slin >> 3;
      int gch = (slin & 7) ^ (row & 7);            // XOR-8 swizzle, conflict-free reads
      u16* la = As + ((p * 256 + (wave << 6)) << 3);
      u16* lb = Bs + ((p * 256 + (wave << 6)) << 3);
      gload_lds16(Arow0 + (size_t)row * Kpad + k0 + gch * 8, la);
      gload_lds16(Brow0 + (size_t)row * Kpad + k0 + gch * 8, lb);
    }
    __syncthreads();
#pragma unroll
    for (int s = 0; s < 2; ++s) {
      bf16x8 af[4], bfr[4];
#pragma unroll
      for (int i = 0; i < 4; ++i) {
        int ar = rbase + i * 16 + m16;
        af[i] = *(const bf16x8*)(As + ar * 64 + (((s * 4 + quad) ^ (ar & 7)) << 3));
        int bc = cbase + i * 16 + m16;
        bfr[i] = *(const bf16x8*)(Bs + bc * 64 + (((s * 4 + quad) ^ (bc & 7)) << 3));
      }
#pragma unroll
      for (int i = 0; i < 4; ++i)
#pragma unroll
        for (int j = 0; j < 4; ++j)
          acc[i][j] = __builtin_amdgcn_mfma_f32_16x16x32_bf16(af[i], bfr[j], acc[i][j], 0, 0, 0);
    }
  }

  float* Cb = C + (size_t)sp * csplit_stride;
#pragma unroll
  for (int i = 0; i < 4; ++i) {
#pragma unroll
    for (int j = 0; j < 4; ++j) {
      int col = nt * 128 + cbase + j * 16 + m16;
      if (col < ncols_valid) {
        int row0 = mt * 128 + rbase + i * 16 + quad * 4;
#pragma unroll
        for (int r = 0; r < 4; ++r)
          Cb[(size_t)(row0 + r) * ldc + col] = acc[i][j][r];
      }
    }
  }
}

extern "C" void kernel_launch(void* const* d_in, const int* in_sizes, int n_in,
                              void* d_out, int out_size, void* d_ws, size_t ws_size,
                              hipStream_t stream) {
  const float* e1   = (const float*)d_in[0];
  const float* rel  = (const float*)d_in[1];
  const float* entw = (const float*)d_in[2];
  const float* fc1w = (const float*)d_in[3];
  const float* fc1b = (const float*)d_in[4];
  const float* fcw  = (const float*)d_in[5];
  // d_in[6] = fc_b: constant per output feature -> cancels under bn2 mean subtraction
  const float* bn0g = (const float*)d_in[7];
  const float* bn0b = (const float*)d_in[8];
  const float* bn1g = (const float*)d_in[9];
  // d_in[10] = bn1_b: beta term is constant per k -> cancels under bn2 mean subtraction
  const float* bn2g = (const float*)d_in[11];
  const float* bn2b = (const float*)d_in[12];
  float* out = (float*)d_out;

  char* ws = (char*)d_ws;
  size_t off = 0;
  auto alloc = [&](size_t bytes) -> void* {
    off = (off + 255) & ~(size_t)255;
    void* p = ws + off;
    off += bytes;
    return p;
  };
  float* stats    = (float*)alloc(16 * 4);
  float* part0    = (float*)alloc(512 * 4);
  float* kbuf     = (float*)alloc((size_t)B_SZ * 288 * 4);
  float* partial1 = (float*)alloc((size_t)B_SZ * 64 * 4);
  float* alphaK   = (float*)alloc((size_t)K_FC * 4);
  u16*   convA    = (u16*)alloc((size_t)B_SZ * K_FC * 2);
  u16*   fcwb     = (u16*)alloc((size_t)NPAD_FC * K_FC * 2);
  float* part2    = (float*)alloc((size_t)SPLIT_FC * B_SZ * NPAD_FC * 4);
  u16*   hfin     = (u16*)alloc((size_t)B_SZ * KPAD_H * 2);
  u16*   entb     = (u16*)alloc((size_t)NPAD_ENT * KPAD_H * 2);

  red0<<<256, 256, 0, stream>>>(e1, part0);
  comb0<<<1, 256, 0, stream>>>(part0, bn0g, bn0b, stats);
  fc1_gemm<<<dim3(16, 5), 256, 0, stream>>>(rel, fc1w, fc1b, kbuf);
  conv_kernel<<<B_SZ, 256, 0, stream>>>(e1, stats, kbuf, convA, partial1);
  comb1<<<1, 256, 0, stream>>>(partial1, bn1g, alphaK);
  cvt_fcw<<<3136, 256, 0, stream>>>(fcw, alphaK, fcwb);
  // fc GEMM: M=1024, N=512(pad of 400), K=12544 -> split-K=14 deterministic partials
  gemm_bt<<<8 * 4 * SPLIT_FC, 256, 0, stream>>>(convA, fcwb, part2, K_FC, 8, 4, 196, 14,
                                                (long)NPAD_FC, NPAD_FC, (long)B_SZ * NPAD_FC, 0);
  bn2_kernel<<<KPAD_H / 16, 256, 0, stream>>>(part2, bn2g, bn2b, hfin);
  cvt_ent<<<10948, 256, 0, stream>>>(entw, entb);
  // final GEMM: M=1024, N=50048(pad of 50000), K=448(pad of 400), XCD-swizzled
  gemm_bt<<<8 * 392, 256, 0, stream>>>(hfin, entb, out, KPAD_H, 8, 391, 7, 7,
                                       (long)N_ENT, N_ENT, 0, 1);
}